// Round 12
// baseline (129.850 us; speedup 1.0000x reference)
//
#include <hip/hip_runtime.h>

typedef unsigned long long ull;

#define N_PRED 25200
#define NCLS   80
#define ROWW   85
#define TOPK   5000
#define IOU_T  0.45f
#define MAXWH  7680.0f

#define K2T    1024
#define MAXE   25     // ceil(25200/1024)
#define CAP    512    // per-(batch,class) bucket storage
#define CAPB   256    // max candidates per (b,c) considered (mean ~62)
#define PTPB   256
#define PROWS  128
#define K4T    1024
#define MAXE4  5      // ceil(5000/1024)
#define SELN   320    // >= max_det
#define SENT   0xFFFFFFFFFFFFFFFFull

__device__ __forceinline__ int SIX(int d) { return d + (d >> 5); }  // conflict-free layout

// ---- descending suffix-scan over nb bins; find digit where cumulative(desc) crosses k
__device__ __forceinline__ void scan_find(const unsigned* hist, int nb, unsigned k, ull* sbd) {
  const int l = (int)threadIdx.x;           // caller guards tid<64
  const int bpl = nb >> 6;
  unsigned s = 0;
  for (int j = 0; j < bpl; ++j) s += hist[SIX(l * bpl + j)];
  unsigned suf = s;
  #pragma unroll
  for (int o = 1; o < 64; o <<= 1) {
    unsigned t = __shfl_down(suf, (unsigned)o, 64);
    if (l + o < 64) suf += t;
  }
  unsigned sufN = __shfl_down(suf, 1u, 64);
  if (l == 63) sufN = 0;
  if (suf >= k && sufN < k) {               // exactly one lane
    unsigned cum = sufN;
    for (int j = bpl - 1; j >= 0; --j) {
      unsigned c = hist[SIX(l * bpl + j)];
      if (cum + c >= k) { sbd[0] = (ull)(l * bpl + j); sbd[1] = (ull)(k - cum); break; }
      cum += c;
    }
  }
}

// ---------------- K1: LDS-staged score/argmax ----------------
__global__ __launch_bounds__(PTPB) void prep_kernel(const float* __restrict__ pred,
    ull* __restrict__ pk, unsigned char* __restrict__ cls8) {
  __shared__ float sr[PROWS * ROWW];   // 43520 B
  const int b = blockIdx.y;
  const int rbase = blockIdx.x * PROWS;
  int nrows = N_PRED - rbase; if (nrows > PROWS) nrows = PROWS;
  const int tid = (int)threadIdx.x;
  const float* src = pred + ((size_t)b * N_PRED + rbase) * ROWW;
  const int nfl4 = (nrows * ROWW) >> 2;   // nrows*85 divisible by 4 (128 or 112 rows)
  for (int i = tid; i < nfl4; i += PTPB) {
    float4 t; __builtin_memcpy(&t, src + i * 4, 16);
    *(float4*)&sr[i * 4] = t;
  }
  __syncthreads();
  const int r = tid >> 1, h = tid & 1;    // 2 threads/row: LDS banks 21r+8h mod 32 -> 2-way (free)
  if (r < nrows) {
    const float* row = sr + r * ROWW;
    float obj = row[4];
    float best = -1.0f; int bi = 0;
    const int c0 = h * 40;
    for (int c = 0; c < 40; ++c) {
      float p = __fmul_rn(row[5 + c0 + c], obj);   // exact: cls_conf = cls * obj
      if (p > best) { best = p; bi = c0 + c; }     // strict > keeps FIRST max within half
    }
    float ob_ = __shfl_xor(best, 1, 64);           // partner lane (pairs 2r,2r+1 same wave)
    int   oi  = __shfl_xor(bi, 1, 64);
    if (h == 0) {
      if (!(best >= ob_)) { best = ob_; bi = oi; } // tie -> half0 (lower index) = jnp.argmax
      bool valid = (obj > 0.25f) && (best > 0.25f);
      float ms = valid ? best : -1.0f;
      unsigned kb = __float_as_uint(ms);
      kb = (kb & 0x80000000u) ? ~kb : (kb | 0x80000000u);   // monotone float->uint
      const int g = rbase + r;
      pk[(size_t)b * N_PRED + g] = ((ull)kb << 32) | (unsigned)~(unsigned)g;
      cls8[(size_t)b * N_PRED + g] = (unsigned char)bi;
    }
  }
}

// ---------------- K2: radix-select top-5000 (wave-aggregated pass-0 hist) + class scatter ----------------
__global__ __launch_bounds__(K2T) void thresh_kernel(const ull* __restrict__ pkArr,
    const unsigned char* __restrict__ cls8, ull* __restrict__ bucket,
    unsigned* __restrict__ bucketCnt, unsigned* __restrict__ keptCnt) {
  __shared__ unsigned hist[2112];
  __shared__ ull sbd[2];
  const int b = blockIdx.x;
  const int tid = (int)threadIdx.x;
  const int lane = tid & 63;
  // zero this batch's counters (block-exclusive; __syncthreads below fences before scatter)
  if (tid < NCLS) bucketCnt[b * NCLS + tid] = 0;
  if (tid == 0) keptCnt[b] = 0;
  ull v[MAXE];
  #pragma unroll
  for (int e = 0; e < MAXE; ++e) {
    int i = tid + e * K2T;
    v[e] = (i < N_PRED) ? pkArr[(size_t)b * N_PRED + i] : 0ull;
  }
  // pass 0: valid-only histogram of bits 63:53, wave-aggregated (keys cluster into ~8 bins;
  // per-lane atomics would serialize same-address -> 52K conflict cycles measured in R11)
  for (int i = tid; i < 2112; i += K2T) hist[i] = 0;
  if (tid == 0) { sbd[0] = SENT; }
  __syncthreads();
  for (int e = 0; e < MAXE; ++e) {
    ull pv = v[e];
    bool act = (pv >> 63) != 0;                 // valid only
    int bin = (int)(pv >> 53);
    ull rem = __ballot(act);
    while (rem) {
      int leader = (int)__ffsll((long long)rem) - 1;
      int lbin = __shfl(bin, leader, 64);
      ull same = __ballot(act && bin == lbin) & rem;
      if (lane == leader) atomicAdd(&hist[SIX(lbin)], (unsigned)__popcll(same));
      rem &= ~same;
    }
  }
  __syncthreads();
  unsigned k = TOPK;
  ull pfx = 0;
  if (tid < 64) scan_find(hist, 2048, k, sbd);
  __syncthreads();
  ull thr;
  if (sbd[0] == SENT) {
    thr = 1ull << 63;                           // < TOPK valid: take all valid
  } else {
    ull d = sbd[0]; unsigned kp = (unsigned)sbd[1];
    unsigned c = hist[SIX((int)d)];
    pfx |= d << 53; k = kp;
    if (kp != c) {   // not whole bin -> refine
      const int shifts[5] = {42, 31, 20, 9, 0};
      const int widths[5] = {11, 11, 11, 11, 9};
      for (int p = 0; p < 5; ++p) {
        const int sh = shifts[p];
        const int nb = 1 << widths[p];
        __syncthreads();
        for (int i = tid; i < 2112; i += K2T) hist[i] = 0;
        __syncthreads();
        const int hb = sh + widths[p];
        const ull hm = ~((1ull << hb) - 1ull);   // hb <= 53
        #pragma unroll
        for (int e = 0; e < MAXE; ++e) {
          ull pv = v[e];
          if ((pv & hm) == pfx)                  // pfx has bit63 set -> invalid/pad never match
            atomicAdd(&hist[SIX((int)((pv >> sh) & (ull)(nb - 1)))], 1u);
        }
        __syncthreads();
        if (tid < 64) scan_find(hist, nb, k, sbd);
        __syncthreads();
        ull d2 = sbd[0]; unsigned kp2 = (unsigned)sbd[1];
        unsigned c2 = hist[SIX((int)d2)];
        pfx |= d2 << sh; k = kp2;
        if (kp2 == c2) break;                    // whole bin taken -> thr exact
      }
    }
    thr = pfx;   // exactly TOPK valid elements have pk >= thr (keys unique)
  }
  // scatter selected into per-class buckets; pv>>63 == validity (ms > 0), = reference tvalid
  #pragma unroll
  for (int e = 0; e < MAXE; ++e) {
    ull pv = v[e];
    if (pv >= thr && (pv >> 63)) {
      unsigned idx = ~(unsigned)(pv & 0xFFFFFFFFull);
      int c = (int)cls8[(size_t)b * N_PRED + idx];
      unsigned pos = atomicAdd(&bucketCnt[b * NCLS + c], 1u);
      if (pos < CAP) bucket[((size_t)b * NCLS + c) * CAP + pos] = pv;
    }
  }
}

// ---------------- K3: per-(batch,class) rank-sort + register-bitmask greedy NMS ----------------
__global__ __launch_bounds__(64) void nms_kernel(const ull* __restrict__ bucket,
    const unsigned* __restrict__ bucketCnt, const float* __restrict__ pred,
    ull* __restrict__ keptPk, float4* __restrict__ keptBox, float2* __restrict__ keptSC,
    unsigned* __restrict__ keptCnt) {
  const int c = blockIdx.x, b = blockIdx.y, lane = (int)threadIdx.x;
  __shared__ ull su[CAPB];      // unsorted
  __shared__ ull spk[CAPB];     // rank-ordered (descending pk)
  __shared__ float4 sob[CAPB];  // offset boxes
  __shared__ float4 srb[CAPB];  // raw boxes
  unsigned kxu = bucketCnt[b * NCLS + c];
  int kx = (kxu > CAPB) ? CAPB : (int)kxu;
  if (kx == 0) return;
  const float cf = (float)c;
  const float off = __fmul_rn(cf, MAXWH);
  const ull* bk = bucket + ((size_t)b * NCLS + c) * CAP;
  for (int i = lane; i < kx; i += 64) su[i] = bk[i];
  __syncthreads();
  // rank-by-count sort (keys unique): rank = #keys greater -> descending order
  {
    ull mine[4]; int rk[4] = {0, 0, 0, 0};
    #pragma unroll
    for (int r = 0; r < 4; ++r) mine[r] = (r * 64 + lane < kx) ? su[r * 64 + lane] : 0ull;
    for (int j = 0; j < kx; ++j) {          // uniform loop, LDS broadcast
      ull x = su[j];
      #pragma unroll
      for (int r = 0; r < 4; ++r) rk[r] += (x > mine[r]) ? 1 : 0;
    }
    #pragma unroll
    for (int r = 0; r < 4; ++r)
      if (r * 64 + lane < kx) spk[rk[r]] = mine[r];
  }
  __syncthreads();
  // single gather: derive raw + offset boxes from pred (bit-identical to reference)
  for (int i = lane; i < kx; i += 64) {
    unsigned idx = ~(unsigned)(spk[i] & 0xFFFFFFFFull);
    float4 t0; __builtin_memcpy(&t0, pred + ((size_t)b * N_PRED + idx) * ROWW, 16);
    float hw = __fmul_rn(t0.z, 0.5f), hh = __fmul_rn(t0.w, 0.5f);
    float4 rb = make_float4(__fsub_rn(t0.x, hw), __fsub_rn(t0.y, hh),
                            __fadd_rn(t0.x, hw), __fadd_rn(t0.y, hh));
    srb[i] = rb;
    sob[i] = make_float4(__fadd_rn(rb.x, off), __fadd_rn(rb.y, off),
                         __fadd_rn(rb.z, off), __fadd_rn(rb.w, off));
  }
  __syncthreads();
  // parallel upper-triangle suppression matrix -> per-lane register masks
  ull rowm[4][4] = {{0ull}};
  #pragma unroll
  for (int r = 0; r < 4; ++r) {
    if (r * 64 < kx) {
      const int i = r * 64 + lane;
      const bool act = i < kx;
      float4 A = sob[act ? i : 0];
      float areaA = __fmul_rn(__fsub_rn(A.z, A.x), __fsub_rn(A.w, A.y));
      #pragma unroll
      for (int w = 0; w < 4; ++w) {
        if (w >= r && w * 64 < kx) {
          ull m = 0ull;
          int jmax = kx - w * 64; if (jmax > 64) jmax = 64;
          for (int jj = 0; jj < jmax; ++jj) {
            const int j = w * 64 + jj;
            float4 Bx = sob[j];             // broadcast read
            float areaB = __fmul_rn(__fsub_rn(Bx.z, Bx.x), __fsub_rn(Bx.w, Bx.y));
            float wx = fmaxf(__fsub_rn(fminf(A.z, Bx.z), fmaxf(A.x, Bx.x)), 0.0f);
            float wy = fmaxf(__fsub_rn(fminf(A.w, Bx.w), fmaxf(A.y, Bx.y)), 0.0f);
            float inter = __fmul_rn(wx, wy);
            float denom = __fadd_rn(__fsub_rn(__fadd_rn(areaA, areaB), inter), 1e-7f);
            float iou = __fdiv_rn(inter, denom);
            if (act && j > i && iou > IOU_T) m |= 1ull << jj;
          }
          rowm[r][w] = m;
        }
      }
    }
  }
  // sequential greedy scan, registers + shfl only (no LDS, no barriers)
  ull alive[4];
  #pragma unroll
  for (int w = 0; w < 4; ++w) {
    int rem = kx - w * 64;
    alive[w] = (rem >= 64) ? ~0ull : (rem > 0 ? ((1ull << rem) - 1ull) : 0ull);
  }
  #pragma unroll
  for (int w = 0; w < 4; ++w) {
    if (w * 64 < kx) {
      int bmax = kx - w * 64; if (bmax > 64) bmax = 64;
      for (int bit = 0; bit < bmax; ++bit) {
        if ((alive[w] >> bit) & 1ull) {     // uniform across lanes
          #pragma unroll
          for (int w2 = 0; w2 < 4; ++w2) {
            if (w2 >= w && w2 * 64 < kx) {
              ull row = __shfl(rowm[w][w2], bit, 64);
              alive[w2] &= ~row;
            }
          }
        }
      }
    }
  }
  // emit kept (order arbitrary; K4 ranks by pk); boxes from LDS
  int tot = 0;
  #pragma unroll
  for (int w = 0; w < 4; ++w) tot += (int)__popcll(alive[w]);
  unsigned gbase = 0;
  if (lane == 0) gbase = atomicAdd(&keptCnt[b], (unsigned)tot);
  gbase = __shfl(gbase, 0, 64);
  unsigned pre = 0;
  #pragma unroll
  for (int w = 0; w < 4; ++w) {
    if (w * 64 < kx) {
      ull aw = alive[w];
      int i = w * 64 + lane;
      bool kp = (i < kx) && ((aw >> lane) & 1ull);
      if (kp) {
        unsigned pos = gbase + pre + (unsigned)__popcll(aw & ((1ull << lane) - 1ull));
        if (pos < TOPK) {
          ull p = spk[i];
          keptPk[(size_t)b * TOPK + pos] = p;
          keptBox[(size_t)b * TOPK + pos] = srb[i];
          keptSC[(size_t)b * TOPK + pos] =
              make_float2(__uint_as_float((unsigned)(p >> 32) & 0x7FFFFFFFu), cf);
        }
      }
      pre += (unsigned)__popcll(aw);
    }
  }
}

// ---------------- K4: top-max_det of kept (radix early-exit + rank-by-count) -> output ----------------
__global__ __launch_bounds__(K4T) void out_kernel(const ull* __restrict__ keptPk,
    const float4* __restrict__ keptBox, const float2* __restrict__ keptSC,
    const unsigned* __restrict__ keptCnt, float* __restrict__ out, int maxdet) {
  __shared__ unsigned hist[2112];
  __shared__ ull sbd[2];
  __shared__ ull sPk[SELN];
  __shared__ int sSlot[SELN];
  __shared__ unsigned scnt;
  const int b = blockIdx.x;
  const int tid = (int)threadIdx.x;
  float* ob = out + (size_t)b * maxdet * 6;
  const unsigned K = keptCnt[b];
  const unsigned kk = (K < (unsigned)maxdet) ? K : (unsigned)maxdet;
  // rows 0..kk-1 are always overwritten; zero only the tail
  for (int i = (int)kk * 6 + tid; i < maxdet * 6; i += K4T) ob[i] = 0.0f;
  if (kk == 0) return;
  ull v[MAXE4];
  #pragma unroll
  for (int e = 0; e < MAXE4; ++e) {
    unsigned i = (unsigned)tid + e * K4T;
    v[e] = (i < K) ? keptPk[(size_t)b * TOPK + i] : 0ull;
  }
  ull thr = 1ull;                       // K <= maxdet: take all (kept pk always nonzero)
  if (K > (unsigned)maxdet) {
    unsigned k = kk;
    ull pfx = 0;
    const int shifts[6] = {53, 42, 31, 20, 9, 0};
    const int widths[6] = {11, 11, 11, 11, 11, 9};
    for (int p = 0; p < 6; ++p) {
      const int sh = shifts[p];
      const int nb = 1 << widths[p];
      for (int i = tid; i < 2112; i += K4T) hist[i] = 0;
      __syncthreads();
      const int hb = sh + widths[p];
      const ull hm = (hb >= 64) ? 0ull : ~((1ull << hb) - 1ull);
      #pragma unroll
      for (int e = 0; e < MAXE4; ++e) {
        ull pv = v[e];
        if (pv != 0ull && (pv & hm) == pfx)
          atomicAdd(&hist[SIX((int)((pv >> sh) & (ull)(nb - 1)))], 1u);
      }
      __syncthreads();
      if (tid < 64) scan_find(hist, nb, k, sbd);
      __syncthreads();
      ull d = sbd[0]; unsigned kp = (unsigned)sbd[1];
      unsigned c = hist[SIX((int)d)];
      pfx |= d << sh; k = kp;
      if (kp == c) break;               // whole bin -> thr exact
      __syncthreads();
    }
    thr = pfx;
  }
  if (tid == 0) scnt = 0;
  __syncthreads();
  const int lane = tid & 63;
  #pragma unroll
  for (int e = 0; e < MAXE4; ++e) {
    unsigned i = (unsigned)tid + e * K4T;
    bool sel = (i < K) && (v[e] >= thr);
    ull m = __ballot(sel);
    if (m) {
      unsigned basep = 0;
      if (lane == 0) basep = atomicAdd(&scnt, (unsigned)__popcll(m));
      basep = __shfl(basep, 0, 64);
      if (sel) {
        unsigned pos = basep + (unsigned)__popcll(m & ((1ull << lane) - 1ull));
        if (pos < SELN) { sPk[pos] = v[e]; sSlot[pos] = (int)i; }
      }
    }
  }
  __syncthreads();
  const int n = (int)scnt;              // == kk (exact threshold, unique keys)
  // rank-by-count: output row = #keys greater (descending pk = reference order)
  for (int i = tid; i < n; i += K4T) {
    ull mypk = sPk[i];
    int rank = 0;
    for (int j = 0; j < n; ++j) rank += (sPk[j] > mypk) ? 1 : 0;   // uniform broadcast
    if (rank < maxdet) {
      int slot = sSlot[i];
      float4 bx = keptBox[(size_t)b * TOPK + slot];
      float2 sc = keptSC[(size_t)b * TOPK + slot];
      float* dst = ob + (size_t)rank * 6;
      dst[0] = bx.x; dst[1] = bx.y; dst[2] = bx.z; dst[3] = bx.w;
      dst[4] = sc.x; dst[5] = sc.y;
    }
  }
}

extern "C" void kernel_launch(void* const* d_in, const int* in_sizes, int n_in,
                              void* d_out, int out_size, void* d_ws, size_t ws_size,
                              hipStream_t stream) {
  const float* pred = (const float*)d_in[0];
  const int B = in_sizes[0] / (N_PRED * ROWW);
  const int maxdet = out_size / (B * 6);

  char* p = (char*)d_ws;
  auto carve = [&](size_t bytes) { char* r = p; p += (bytes + 255) & ~(size_t)255; return (void*)r; };
  ull*           pk       = (ull*)carve((size_t)B * N_PRED * 8);
  unsigned char* cls8     = (unsigned char*)carve((size_t)B * N_PRED);
  unsigned*      bucketCnt= (unsigned*)carve((size_t)B * NCLS * 4);
  unsigned*      keptCnt  = (unsigned*)carve((size_t)B * 4);
  ull*      bucket  = (ull*)carve((size_t)B * NCLS * CAP * 8);
  ull*      keptPk  = (ull*)carve((size_t)B * TOPK * 8);
  float4*   keptBox = (float4*)carve((size_t)B * TOPK * 16);
  float2*   keptSC  = (float2*)carve((size_t)B * TOPK * 8);

  prep_kernel<<<dim3((N_PRED + PROWS - 1) / PROWS, B), PTPB, 0, stream>>>(pred, pk, cls8);
  thresh_kernel<<<B, K2T, 0, stream>>>(pk, cls8, bucket, bucketCnt, keptCnt);
  nms_kernel<<<dim3(NCLS, B), 64, 0, stream>>>(bucket, bucketCnt, pred,
                                               keptPk, keptBox, keptSC, keptCnt);
  out_kernel<<<B, K4T, 0, stream>>>(keptPk, keptBox, keptSC, keptCnt, (float*)d_out, maxdet);
}

// Round 13
// 108.676 us; speedup vs baseline: 1.1948x; 1.1948x over previous
//
#include <hip/hip_runtime.h>

typedef unsigned long long ull;

#define N_PRED 25200
#define NCLS   80
#define ROWW   85
#define TOPK   5000
#define IOU_T  0.45f
#define MAXWH  7680.0f

#define K2T    1024
#define MAXE   25     // ceil(25200/1024)
#define CAP    512    // per-(batch,class) bucket storage
#define CAPB   256    // max candidates per (b,c) considered (mean ~62)
#define PTPB   256
#define PROWS  128
#define K4T    1024
#define MAXE4  5      // ceil(5000/1024)
#define SELN   320    // >= max_det

__device__ __forceinline__ int SIX(int d) { return d + (d >> 5); }  // conflict-free layout

// ---- descending suffix-scan over nb bins; find digit where cumulative(desc) crosses k
__device__ __forceinline__ void scan_find(const unsigned* hist, int nb, unsigned k, ull* sbd) {
  const int l = (int)threadIdx.x;           // caller guards tid<64
  const int bpl = nb >> 6;
  unsigned s = 0;
  for (int j = 0; j < bpl; ++j) s += hist[SIX(l * bpl + j)];
  unsigned suf = s;
  #pragma unroll
  for (int o = 1; o < 64; o <<= 1) {
    unsigned t = __shfl_down(suf, (unsigned)o, 64);
    if (l + o < 64) suf += t;
  }
  unsigned sufN = __shfl_down(suf, 1u, 64);
  if (l == 63) sufN = 0;
  if (suf >= k && sufN < k) {               // exactly one lane
    unsigned cum = sufN;
    for (int j = bpl - 1; j >= 0; --j) {
      unsigned c = hist[SIX(l * bpl + j)];
      if (cum + c >= k) { sbd[0] = (ull)(l * bpl + j); sbd[1] = (ull)(k - cum); break; }
      cum += c;
    }
  }
}

// ---------------- K1: LDS-staged score/argmax ----------------
__global__ __launch_bounds__(PTPB) void prep_kernel(const float* __restrict__ pred,
    ull* __restrict__ pk, unsigned char* __restrict__ cls8) {
  __shared__ float sr[PROWS * ROWW];   // 43520 B
  const int b = blockIdx.y;
  const int rbase = blockIdx.x * PROWS;
  int nrows = N_PRED - rbase; if (nrows > PROWS) nrows = PROWS;
  const int tid = (int)threadIdx.x;
  const float* src = pred + ((size_t)b * N_PRED + rbase) * ROWW;
  const int nfl4 = (nrows * ROWW) >> 2;   // nrows*85 divisible by 4 (128 or 112 rows)
  for (int i = tid; i < nfl4; i += PTPB) {
    float4 t; __builtin_memcpy(&t, src + i * 4, 16);
    *(float4*)&sr[i * 4] = t;
  }
  __syncthreads();
  const int r = tid >> 1, h = tid & 1;    // 2 threads/row: LDS banks 21r+8h mod 32 -> 2-way (free)
  if (r < nrows) {
    const float* row = sr + r * ROWW;
    float obj = row[4];
    float best = -1.0f; int bi = 0;
    const int c0 = h * 40;
    for (int c = 0; c < 40; ++c) {
      float p = __fmul_rn(row[5 + c0 + c], obj);   // exact: cls_conf = cls * obj
      if (p > best) { best = p; bi = c0 + c; }     // strict > keeps FIRST max within half
    }
    float ob_ = __shfl_xor(best, 1, 64);           // partner lane (pairs 2r,2r+1 same wave)
    int   oi  = __shfl_xor(bi, 1, 64);
    if (h == 0) {
      if (!(best >= ob_)) { best = ob_; bi = oi; } // tie -> half0 (lower index) = jnp.argmax
      bool valid = (obj > 0.25f) && (best > 0.25f);
      float ms = valid ? best : -1.0f;
      unsigned kb = __float_as_uint(ms);
      kb = (kb & 0x80000000u) ? ~kb : (kb | 0x80000000u);   // monotone float->uint
      const int g = rbase + r;
      pk[(size_t)b * N_PRED + g] = ((ull)kb << 32) | (unsigned)~(unsigned)g;
      cls8[(size_t)b * N_PRED + g] = (unsigned char)bi;
    }
  }
}

// ---------------- K2: radix-select top-5000 (register-window pass-0) + class scatter ----------------
__global__ __launch_bounds__(K2T) void thresh_kernel(const ull* __restrict__ pkArr,
    const unsigned char* __restrict__ cls8, ull* __restrict__ bucket,
    unsigned* __restrict__ bucketCnt, unsigned* __restrict__ keptCnt) {
  __shared__ unsigned hist[2112];
  __shared__ ull sbd[2];
  __shared__ int swm[16];          // per-wave max bin
  __shared__ unsigned swc[16][12]; // per-wave counters: win[0..7], below, (pad)
  __shared__ unsigned stot[9];
  __shared__ int sbase;
  __shared__ int scase;            // 0 = window hit, 1 = take-all-valid, 2 = fallback low bins
  __shared__ unsigned scnt0;
  const int b = blockIdx.x;
  const int tid = (int)threadIdx.x;
  const int lane = tid & 63, wv = tid >> 6;
  // zero this batch's counters (block-exclusive; __syncthreads below fences before scatter)
  if (tid < NCLS) bucketCnt[b * NCLS + tid] = 0;
  if (tid == 0) keptCnt[b] = 0;
  ull v[MAXE];
  #pragma unroll
  for (int e = 0; e < MAXE; ++e) {
    int i = tid + e * K2T;
    v[e] = (i < N_PRED) ? pkArr[(size_t)b * N_PRED + i] : 0ull;
  }
  // ---- pass 0a: block max valid bin (bits 63:53)
  int mymax = -1;
  #pragma unroll
  for (int e = 0; e < MAXE; ++e)
    if (v[e] >> 63) { int bin = (int)(v[e] >> 53); if (bin > mymax) mymax = bin; }
  #pragma unroll
  for (int o = 32; o; o >>= 1) { int t = __shfl_xor(mymax, o, 64); if (t > mymax) mymax = t; }
  if (lane == 0) swm[wv] = mymax;
  __syncthreads();
  if (tid == 0) {
    int g = -1;
    for (int w = 0; w < 16; ++w) if (swm[w] > g) g = swm[w];
    sbase = (g >= 7) ? g - 7 : 0;
    scase = (g < 0) ? 1 : 0;       // no valid at all -> take-all (selects nothing)
  }
  __syncthreads();
  const int base = sbase;
  if (scase == 0) {
    // ---- pass 0b: register-window count (independent compare-adds, no atomics, no chains)
    unsigned c[8] = {0,0,0,0,0,0,0,0}, clow = 0;
    #pragma unroll
    for (int e = 0; e < MAXE; ++e) {
      ull pv = v[e];
      if (pv >> 63) {
        int d = (int)(pv >> 53) - base;
        if (d < 0) clow++;
        else {
          #pragma unroll
          for (int j = 0; j < 8; ++j) c[j] += (d == j) ? 1u : 0u;
        }
      }
    }
    #pragma unroll
    for (int j = 0; j < 8; ++j)
      #pragma unroll
      for (int o = 32; o; o >>= 1) c[j] += __shfl_xor(c[j], o, 64);
    #pragma unroll
    for (int o = 32; o; o >>= 1) clow += __shfl_xor(clow, o, 64);
    if (lane == 0) {
      #pragma unroll
      for (int j = 0; j < 8; ++j) swc[wv][j] = c[j];
      swc[wv][8] = clow;
    }
    __syncthreads();
    if (tid < 9) {
      unsigned s = 0;
      for (int w = 0; w < 16; ++w) s += swc[w][tid];
      stot[tid] = s;
    }
    __syncthreads();
    if (tid == 0) {
      unsigned cum = 0; int jstar = -1; unsigned kp = 0;
      for (int j = 7; j >= 0; --j) {
        if (cum + stot[j] >= (unsigned)TOPK) { jstar = j; kp = (unsigned)TOPK - cum; break; }
        cum += stot[j];
      }
      if (jstar >= 0) {
        scase = 0; sbd[0] = (ull)(base + jstar); sbd[1] = (ull)kp; scnt0 = stot[jstar];
      } else {
        unsigned S0 = cum;             // total valid in window
        if (S0 + stot[8] < (unsigned)TOPK) { scase = 1; }   // < TOPK valid: take all
        else { scase = 2; sbd[1] = (ull)((unsigned)TOPK - S0); }  // crossing below window (rare)
      }
    }
    __syncthreads();
  }
  ull thr;
  if (scase == 1) {
    thr = 1ull << 63;                  // take all valid
  } else {
    ull pfx; unsigned k, cnt0;
    if (scase == 2) {                  // rare general fallback: histogram bins < base
      unsigned k2 = (unsigned)sbd[1];
      for (int i = tid; i < 2112; i += K2T) hist[i] = 0;
      __syncthreads();
      #pragma unroll
      for (int e = 0; e < MAXE; ++e) {
        ull pv = v[e];
        if ((pv >> 63) && (int)(pv >> 53) < base)
          atomicAdd(&hist[SIX((int)(pv >> 53))], 1u);
      }
      __syncthreads();
      if (tid < 64) scan_find(hist, 2048, k2, sbd);
      __syncthreads();
      pfx = sbd[0] << 53; k = (unsigned)sbd[1]; cnt0 = hist[SIX((int)sbd[0])];
      __syncthreads();
    } else {
      pfx = sbd[0] << 53; k = (unsigned)sbd[1]; cnt0 = scnt0;
    }
    if (k != cnt0) {   // not whole bin -> refine bits below 53
      const int shifts[5] = {42, 31, 20, 9, 0};
      const int widths[5] = {11, 11, 11, 11, 9};
      for (int p = 0; p < 5; ++p) {
        const int sh = shifts[p];
        const int nb = 1 << widths[p];
        __syncthreads();
        for (int i = tid; i < 2112; i += K2T) hist[i] = 0;
        __syncthreads();
        const int hb = sh + widths[p];
        const ull hm = ~((1ull << hb) - 1ull);   // hb <= 53
        #pragma unroll
        for (int e = 0; e < MAXE; ++e) {
          ull pv = v[e];
          if ((pv & hm) == pfx)                  // pfx has bit63 set -> invalid/pad never match
            atomicAdd(&hist[SIX((int)((pv >> sh) & (ull)(nb - 1)))], 1u);
        }
        __syncthreads();
        if (tid < 64) scan_find(hist, nb, k, sbd);
        __syncthreads();
        ull d2 = sbd[0]; unsigned kp2 = (unsigned)sbd[1];
        unsigned c2 = hist[SIX((int)d2)];
        pfx |= d2 << sh; k = kp2;
        if (kp2 == c2) break;                    // whole bin taken -> thr exact
      }
    }
    thr = pfx;   // exactly TOPK valid elements have pk >= thr (keys unique)
  }
  // scatter selected into per-class buckets; pv>>63 == validity (ms > 0), = reference tvalid
  #pragma unroll
  for (int e = 0; e < MAXE; ++e) {
    ull pv = v[e];
    if (pv >= thr && (pv >> 63)) {
      unsigned idx = ~(unsigned)(pv & 0xFFFFFFFFull);
      int c = (int)cls8[(size_t)b * N_PRED + idx];
      unsigned pos = atomicAdd(&bucketCnt[b * NCLS + c], 1u);
      if (pos < CAP) bucket[((size_t)b * NCLS + c) * CAP + pos] = pv;
    }
  }
}

// ---------------- K3: per-(batch,class) rank-sort + register-bitmask greedy NMS ----------------
__global__ __launch_bounds__(64) void nms_kernel(const ull* __restrict__ bucket,
    const unsigned* __restrict__ bucketCnt, const float* __restrict__ pred,
    ull* __restrict__ keptPk, float4* __restrict__ keptBox, float2* __restrict__ keptSC,
    unsigned* __restrict__ keptCnt) {
  const int c = blockIdx.x, b = blockIdx.y, lane = (int)threadIdx.x;
  __shared__ ull su[CAPB];      // unsorted
  __shared__ ull spk[CAPB];     // rank-ordered (descending pk)
  __shared__ float4 sob[CAPB];  // offset boxes
  __shared__ float4 srb[CAPB];  // raw boxes
  unsigned kxu = bucketCnt[b * NCLS + c];
  int kx = (kxu > CAPB) ? CAPB : (int)kxu;
  if (kx == 0) return;
  const float cf = (float)c;
  const float off = __fmul_rn(cf, MAXWH);
  const ull* bk = bucket + ((size_t)b * NCLS + c) * CAP;
  for (int i = lane; i < kx; i += 64) su[i] = bk[i];
  __syncthreads();
  // rank-by-count sort (keys unique): rank = #keys greater -> descending order
  {
    ull mine[4]; int rk[4] = {0, 0, 0, 0};
    #pragma unroll
    for (int r = 0; r < 4; ++r) mine[r] = (r * 64 + lane < kx) ? su[r * 64 + lane] : 0ull;
    for (int j = 0; j < kx; ++j) {          // uniform loop, LDS broadcast
      ull x = su[j];
      #pragma unroll
      for (int r = 0; r < 4; ++r) rk[r] += (x > mine[r]) ? 1 : 0;
    }
    #pragma unroll
    for (int r = 0; r < 4; ++r)
      if (r * 64 + lane < kx) spk[rk[r]] = mine[r];
  }
  __syncthreads();
  // single gather: derive raw + offset boxes from pred (bit-identical to reference)
  for (int i = lane; i < kx; i += 64) {
    unsigned idx = ~(unsigned)(spk[i] & 0xFFFFFFFFull);
    float4 t0; __builtin_memcpy(&t0, pred + ((size_t)b * N_PRED + idx) * ROWW, 16);
    float hw = __fmul_rn(t0.z, 0.5f), hh = __fmul_rn(t0.w, 0.5f);
    float4 rb = make_float4(__fsub_rn(t0.x, hw), __fsub_rn(t0.y, hh),
                            __fadd_rn(t0.x, hw), __fadd_rn(t0.y, hh));
    srb[i] = rb;
    sob[i] = make_float4(__fadd_rn(rb.x, off), __fadd_rn(rb.y, off),
                         __fadd_rn(rb.z, off), __fadd_rn(rb.w, off));
  }
  __syncthreads();
  // parallel upper-triangle suppression matrix -> per-lane register masks
  ull rowm[4][4] = {{0ull}};
  #pragma unroll
  for (int r = 0; r < 4; ++r) {
    if (r * 64 < kx) {
      const int i = r * 64 + lane;
      const bool act = i < kx;
      float4 A = sob[act ? i : 0];
      float areaA = __fmul_rn(__fsub_rn(A.z, A.x), __fsub_rn(A.w, A.y));
      #pragma unroll
      for (int w = 0; w < 4; ++w) {
        if (w >= r && w * 64 < kx) {
          ull m = 0ull;
          int jmax = kx - w * 64; if (jmax > 64) jmax = 64;
          for (int jj = 0; jj < jmax; ++jj) {
            const int j = w * 64 + jj;
            float4 Bx = sob[j];             // broadcast read
            float areaB = __fmul_rn(__fsub_rn(Bx.z, Bx.x), __fsub_rn(Bx.w, Bx.y));
            float wx = fmaxf(__fsub_rn(fminf(A.z, Bx.z), fmaxf(A.x, Bx.x)), 0.0f);
            float wy = fmaxf(__fsub_rn(fminf(A.w, Bx.w), fmaxf(A.y, Bx.y)), 0.0f);
            float inter = __fmul_rn(wx, wy);
            float denom = __fadd_rn(__fsub_rn(__fadd_rn(areaA, areaB), inter), 1e-7f);
            float iou = __fdiv_rn(inter, denom);
            if (act && j > i && iou > IOU_T) m |= 1ull << jj;
          }
          rowm[r][w] = m;
        }
      }
    }
  }
  // sequential greedy scan, registers + shfl only (no LDS, no barriers)
  ull alive[4];
  #pragma unroll
  for (int w = 0; w < 4; ++w) {
    int rem = kx - w * 64;
    alive[w] = (rem >= 64) ? ~0ull : (rem > 0 ? ((1ull << rem) - 1ull) : 0ull);
  }
  #pragma unroll
  for (int w = 0; w < 4; ++w) {
    if (w * 64 < kx) {
      int bmax = kx - w * 64; if (bmax > 64) bmax = 64;
      for (int bit = 0; bit < bmax; ++bit) {
        if ((alive[w] >> bit) & 1ull) {     // uniform across lanes
          #pragma unroll
          for (int w2 = 0; w2 < 4; ++w2) {
            if (w2 >= w && w2 * 64 < kx) {
              ull row = __shfl(rowm[w][w2], bit, 64);
              alive[w2] &= ~row;
            }
          }
        }
      }
    }
  }
  // emit kept (order arbitrary; K4 ranks by pk); boxes from LDS
  int tot = 0;
  #pragma unroll
  for (int w = 0; w < 4; ++w) tot += (int)__popcll(alive[w]);
  unsigned gbase = 0;
  if (lane == 0) gbase = atomicAdd(&keptCnt[b], (unsigned)tot);
  gbase = __shfl(gbase, 0, 64);
  unsigned pre = 0;
  #pragma unroll
  for (int w = 0; w < 4; ++w) {
    if (w * 64 < kx) {
      ull aw = alive[w];
      int i = w * 64 + lane;
      bool kp = (i < kx) && ((aw >> lane) & 1ull);
      if (kp) {
        unsigned pos = gbase + pre + (unsigned)__popcll(aw & ((1ull << lane) - 1ull));
        if (pos < TOPK) {
          ull p = spk[i];
          keptPk[(size_t)b * TOPK + pos] = p;
          keptBox[(size_t)b * TOPK + pos] = srb[i];
          keptSC[(size_t)b * TOPK + pos] =
              make_float2(__uint_as_float((unsigned)(p >> 32) & 0x7FFFFFFFu), cf);
        }
      }
      pre += (unsigned)__popcll(aw);
    }
  }
}

// ---------------- K4: top-max_det of kept (radix early-exit + rank-by-count) -> output ----------------
__global__ __launch_bounds__(K4T) void out_kernel(const ull* __restrict__ keptPk,
    const float4* __restrict__ keptBox, const float2* __restrict__ keptSC,
    const unsigned* __restrict__ keptCnt, float* __restrict__ out, int maxdet) {
  __shared__ unsigned hist[2112];
  __shared__ ull sbd[2];
  __shared__ ull sPk[SELN];
  __shared__ int sSlot[SELN];
  __shared__ unsigned scnt;
  const int b = blockIdx.x;
  const int tid = (int)threadIdx.x;
  float* ob = out + (size_t)b * maxdet * 6;
  const unsigned K = keptCnt[b];
  const unsigned kk = (K < (unsigned)maxdet) ? K : (unsigned)maxdet;
  // rows 0..kk-1 are always overwritten; zero only the tail
  for (int i = (int)kk * 6 + tid; i < maxdet * 6; i += K4T) ob[i] = 0.0f;
  if (kk == 0) return;
  ull v[MAXE4];
  #pragma unroll
  for (int e = 0; e < MAXE4; ++e) {
    unsigned i = (unsigned)tid + e * K4T;
    v[e] = (i < K) ? keptPk[(size_t)b * TOPK + i] : 0ull;
  }
  ull thr = 1ull;                       // K <= maxdet: take all (kept pk always nonzero)
  if (K > (unsigned)maxdet) {
    unsigned k = kk;
    ull pfx = 0;
    const int shifts[6] = {53, 42, 31, 20, 9, 0};
    const int widths[6] = {11, 11, 11, 11, 11, 9};
    for (int p = 0; p < 6; ++p) {
      const int sh = shifts[p];
      const int nb = 1 << widths[p];
      for (int i = tid; i < 2112; i += K4T) hist[i] = 0;
      __syncthreads();
      const int hb = sh + widths[p];
      const ull hm = (hb >= 64) ? 0ull : ~((1ull << hb) - 1ull);
      #pragma unroll
      for (int e = 0; e < MAXE4; ++e) {
        ull pv = v[e];
        if (pv != 0ull && (pv & hm) == pfx)
          atomicAdd(&hist[SIX((int)((pv >> sh) & (ull)(nb - 1)))], 1u);
      }
      __syncthreads();
      if (tid < 64) scan_find(hist, nb, k, sbd);
      __syncthreads();
      ull d = sbd[0]; unsigned kp = (unsigned)sbd[1];
      unsigned c = hist[SIX((int)d)];
      pfx |= d << sh; k = kp;
      if (kp == c) break;               // whole bin -> thr exact
      __syncthreads();
    }
    thr = pfx;
  }
  if (tid == 0) scnt = 0;
  __syncthreads();
  const int lane = tid & 63;
  #pragma unroll
  for (int e = 0; e < MAXE4; ++e) {
    unsigned i = (unsigned)tid + e * K4T;
    bool sel = (i < K) && (v[e] >= thr);
    ull m = __ballot(sel);
    if (m) {
      unsigned basep = 0;
      if (lane == 0) basep = atomicAdd(&scnt, (unsigned)__popcll(m));
      basep = __shfl(basep, 0, 64);
      if (sel) {
        unsigned pos = basep + (unsigned)__popcll(m & ((1ull << lane) - 1ull));
        if (pos < SELN) { sPk[pos] = v[e]; sSlot[pos] = (int)i; }
      }
    }
  }
  __syncthreads();
  const int n = (int)scnt;              // == kk (exact threshold, unique keys)
  // rank-by-count: output row = #keys greater (descending pk = reference order)
  for (int i = tid; i < n; i += K4T) {
    ull mypk = sPk[i];
    int rank = 0;
    for (int j = 0; j < n; ++j) rank += (sPk[j] > mypk) ? 1 : 0;   // uniform broadcast
    if (rank < maxdet) {
      int slot = sSlot[i];
      float4 bx = keptBox[(size_t)b * TOPK + slot];
      float2 sc = keptSC[(size_t)b * TOPK + slot];
      float* dst = ob + (size_t)rank * 6;
      dst[0] = bx.x; dst[1] = bx.y; dst[2] = bx.z; dst[3] = bx.w;
      dst[4] = sc.x; dst[5] = sc.y;
    }
  }
}

extern "C" void kernel_launch(void* const* d_in, const int* in_sizes, int n_in,
                              void* d_out, int out_size, void* d_ws, size_t ws_size,
                              hipStream_t stream) {
  const float* pred = (const float*)d_in[0];
  const int B = in_sizes[0] / (N_PRED * ROWW);
  const int maxdet = out_size / (B * 6);

  char* p = (char*)d_ws;
  auto carve = [&](size_t bytes) { char* r = p; p += (bytes + 255) & ~(size_t)255; return (void*)r; };
  ull*           pk       = (ull*)carve((size_t)B * N_PRED * 8);
  unsigned char* cls8     = (unsigned char*)carve((size_t)B * N_PRED);
  unsigned*      bucketCnt= (unsigned*)carve((size_t)B * NCLS * 4);
  unsigned*      keptCnt  = (unsigned*)carve((size_t)B * 4);
  ull*      bucket  = (ull*)carve((size_t)B * NCLS * CAP * 8);
  ull*      keptPk  = (ull*)carve((size_t)B * TOPK * 8);
  float4*   keptBox = (float4*)carve((size_t)B * TOPK * 16);
  float2*   keptSC  = (float2*)carve((size_t)B * TOPK * 8);

  prep_kernel<<<dim3((N_PRED + PROWS - 1) / PROWS, B), PTPB, 0, stream>>>(pred, pk, cls8);
  thresh_kernel<<<B, K2T, 0, stream>>>(pk, cls8, bucket, bucketCnt, keptCnt);
  nms_kernel<<<dim3(NCLS, B), 64, 0, stream>>>(bucket, bucketCnt, pred,
                                               keptPk, keptBox, keptSC, keptCnt);
  out_kernel<<<B, K4T, 0, stream>>>(keptPk, keptBox, keptSC, keptCnt, (float*)d_out, maxdet);
}

// Round 14
// 100.383 us; speedup vs baseline: 1.2935x; 1.0826x over previous
//
#include <hip/hip_runtime.h>

typedef unsigned long long ull;

#define N_PRED 25200
#define NCLS   80
#define ROWW   85
#define TOPK   5000
#define IOU_T  0.45f
#define MAXWH  7680.0f

#define K2T    1024
#define MAXE   25     // ceil(25200/1024)
#define CAP    512    // per-(batch,class) bucket storage
#define CAPB   256    // max candidates per (b,c) considered (mean ~62)
#define PTPB   256
#define PROWS  128
#define K4T    1024
#define MAXE4  5      // ceil(5000/1024)
#define SELN   320    // >= max_det

__device__ __forceinline__ int SIX(int d) { return d + (d >> 5); }  // conflict-free layout

// ---- descending suffix-scan over nb bins; find digit where cumulative(desc) crosses k
__device__ __forceinline__ void scan_find(const unsigned* hist, int nb, unsigned k, ull* sbd) {
  const int l = (int)threadIdx.x;           // caller guards tid<64
  const int bpl = nb >> 6;
  unsigned s = 0;
  for (int j = 0; j < bpl; ++j) s += hist[SIX(l * bpl + j)];
  unsigned suf = s;
  #pragma unroll
  for (int o = 1; o < 64; o <<= 1) {
    unsigned t = __shfl_down(suf, (unsigned)o, 64);
    if (l + o < 64) suf += t;
  }
  unsigned sufN = __shfl_down(suf, 1u, 64);
  if (l == 63) sufN = 0;
  if (suf >= k && sufN < k) {               // exactly one lane
    unsigned cum = sufN;
    for (int j = bpl - 1; j >= 0; --j) {
      unsigned c = hist[SIX(l * bpl + j)];
      if (cum + c >= k) { sbd[0] = (ull)(l * bpl + j); sbd[1] = (ull)(k - cum); break; }
      cum += c;
    }
  }
}

// ---------------- K1: LDS-staged score/argmax ----------------
__global__ __launch_bounds__(PTPB) void prep_kernel(const float* __restrict__ pred,
    ull* __restrict__ pk, unsigned char* __restrict__ cls8) {
  __shared__ float sr[PROWS * ROWW];   // 43520 B
  const int b = blockIdx.y;
  const int rbase = blockIdx.x * PROWS;
  int nrows = N_PRED - rbase; if (nrows > PROWS) nrows = PROWS;
  const int tid = (int)threadIdx.x;
  const float* src = pred + ((size_t)b * N_PRED + rbase) * ROWW;
  const int nfl4 = (nrows * ROWW) >> 2;   // nrows*85 divisible by 4 (128 or 112 rows)
  for (int i = tid; i < nfl4; i += PTPB) {
    float4 t; __builtin_memcpy(&t, src + i * 4, 16);
    *(float4*)&sr[i * 4] = t;
  }
  __syncthreads();
  const int r = tid >> 1, h = tid & 1;    // 2 threads/row: LDS banks 21r+8h mod 32 -> 2-way (free)
  if (r < nrows) {
    const float* row = sr + r * ROWW;
    float obj = row[4];
    float best = -1.0f; int bi = 0;
    const int c0 = h * 40;
    for (int c = 0; c < 40; ++c) {
      float p = __fmul_rn(row[5 + c0 + c], obj);   // exact: cls_conf = cls * obj
      if (p > best) { best = p; bi = c0 + c; }     // strict > keeps FIRST max within half
    }
    float ob_ = __shfl_xor(best, 1, 64);           // partner lane (pairs 2r,2r+1 same wave)
    int   oi  = __shfl_xor(bi, 1, 64);
    if (h == 0) {
      if (!(best >= ob_)) { best = ob_; bi = oi; } // tie -> half0 (lower index) = jnp.argmax
      bool valid = (obj > 0.25f) && (best > 0.25f);
      float ms = valid ? best : -1.0f;
      unsigned kb = __float_as_uint(ms);
      kb = (kb & 0x80000000u) ? ~kb : (kb | 0x80000000u);   // monotone float->uint
      const int g = rbase + r;
      pk[(size_t)b * N_PRED + g] = ((ull)kb << 32) | (unsigned)~(unsigned)g;
      cls8[(size_t)b * N_PRED + g] = (unsigned char)bi;
    }
  }
}

// ---------------- K2a: radix-select top-5000 threshold only (register-window pass-0) ----------------
__global__ __launch_bounds__(K2T) void thresh_kernel(const ull* __restrict__ pkArr,
    ull* __restrict__ thrKey, unsigned* __restrict__ bucketCnt, unsigned* __restrict__ keptCnt) {
  __shared__ unsigned hist[2112];
  __shared__ ull sbd[2];
  __shared__ int swm[16];          // per-wave max bin
  __shared__ unsigned swc[16][12]; // per-wave counters: win[0..7], below, (pad)
  __shared__ unsigned stot[9];
  __shared__ int sbase;
  __shared__ int scase;            // 0 = window hit, 1 = take-all-valid, 2 = fallback low bins
  __shared__ unsigned scnt0;
  const int b = blockIdx.x;
  const int tid = (int)threadIdx.x;
  const int lane = tid & 63, wv = tid >> 6;
  // zero this batch's counters (scatter runs in a later kernel -> stream order guarantees visibility)
  if (tid < NCLS) bucketCnt[b * NCLS + tid] = 0;
  if (tid == 0) keptCnt[b] = 0;
  ull v[MAXE];
  #pragma unroll
  for (int e = 0; e < MAXE; ++e) {
    int i = tid + e * K2T;
    v[e] = (i < N_PRED) ? pkArr[(size_t)b * N_PRED + i] : 0ull;
  }
  // ---- pass 0a: block max valid bin (bits 63:53)
  int mymax = -1;
  #pragma unroll
  for (int e = 0; e < MAXE; ++e)
    if (v[e] >> 63) { int bin = (int)(v[e] >> 53); if (bin > mymax) mymax = bin; }
  #pragma unroll
  for (int o = 32; o; o >>= 1) { int t = __shfl_xor(mymax, o, 64); if (t > mymax) mymax = t; }
  if (lane == 0) swm[wv] = mymax;
  __syncthreads();
  if (tid == 0) {
    int g = -1;
    for (int w = 0; w < 16; ++w) if (swm[w] > g) g = swm[w];
    sbase = (g >= 7) ? g - 7 : 0;
    scase = (g < 0) ? 1 : 0;       // no valid at all -> take-all (selects nothing)
  }
  __syncthreads();
  const int base = sbase;
  if (scase == 0) {
    // ---- pass 0b: register-window count (independent compare-adds, no atomics, no chains)
    unsigned c[8] = {0,0,0,0,0,0,0,0}, clow = 0;
    #pragma unroll
    for (int e = 0; e < MAXE; ++e) {
      ull pv = v[e];
      if (pv >> 63) {
        int d = (int)(pv >> 53) - base;
        if (d < 0) clow++;
        else {
          #pragma unroll
          for (int j = 0; j < 8; ++j) c[j] += (d == j) ? 1u : 0u;
        }
      }
    }
    #pragma unroll
    for (int j = 0; j < 8; ++j)
      #pragma unroll
      for (int o = 32; o; o >>= 1) c[j] += __shfl_xor(c[j], o, 64);
    #pragma unroll
    for (int o = 32; o; o >>= 1) clow += __shfl_xor(clow, o, 64);
    if (lane == 0) {
      #pragma unroll
      for (int j = 0; j < 8; ++j) swc[wv][j] = c[j];
      swc[wv][8] = clow;
    }
    __syncthreads();
    if (tid < 9) {
      unsigned s = 0;
      for (int w = 0; w < 16; ++w) s += swc[w][tid];
      stot[tid] = s;
    }
    __syncthreads();
    if (tid == 0) {
      unsigned cum = 0; int jstar = -1; unsigned kp = 0;
      for (int j = 7; j >= 0; --j) {
        if (cum + stot[j] >= (unsigned)TOPK) { jstar = j; kp = (unsigned)TOPK - cum; break; }
        cum += stot[j];
      }
      if (jstar >= 0) {
        scase = 0; sbd[0] = (ull)(base + jstar); sbd[1] = (ull)kp; scnt0 = stot[jstar];
      } else {
        unsigned S0 = cum;             // total valid in window
        if (S0 + stot[8] < (unsigned)TOPK) { scase = 1; }   // < TOPK valid: take all
        else { scase = 2; sbd[1] = (ull)((unsigned)TOPK - S0); }  // crossing below window (rare)
      }
    }
    __syncthreads();
  }
  ull thr;
  if (scase == 1) {
    thr = 1ull << 63;                  // take all valid
  } else {
    ull pfx; unsigned k, cnt0;
    if (scase == 2) {                  // rare general fallback: histogram bins < base
      unsigned k2 = (unsigned)sbd[1];
      for (int i = tid; i < 2112; i += K2T) hist[i] = 0;
      __syncthreads();
      #pragma unroll
      for (int e = 0; e < MAXE; ++e) {
        ull pv = v[e];
        if ((pv >> 63) && (int)(pv >> 53) < base)
          atomicAdd(&hist[SIX((int)(pv >> 53))], 1u);
      }
      __syncthreads();
      if (tid < 64) scan_find(hist, 2048, k2, sbd);
      __syncthreads();
      pfx = sbd[0] << 53; k = (unsigned)sbd[1]; cnt0 = hist[SIX((int)sbd[0])];
      __syncthreads();
    } else {
      pfx = sbd[0] << 53; k = (unsigned)sbd[1]; cnt0 = scnt0;
    }
    if (k != cnt0) {   // not whole bin -> refine bits below 53
      const int shifts[5] = {42, 31, 20, 9, 0};
      const int widths[5] = {11, 11, 11, 11, 9};
      for (int p = 0; p < 5; ++p) {
        const int sh = shifts[p];
        const int nb = 1 << widths[p];
        __syncthreads();
        for (int i = tid; i < 2112; i += K2T) hist[i] = 0;
        __syncthreads();
        const int hb = sh + widths[p];
        const ull hm = ~((1ull << hb) - 1ull);   // hb <= 53
        #pragma unroll
        for (int e = 0; e < MAXE; ++e) {
          ull pv = v[e];
          if ((pv & hm) == pfx)                  // pfx has bit63 set -> invalid/pad never match
            atomicAdd(&hist[SIX((int)((pv >> sh) & (ull)(nb - 1)))], 1u);
        }
        __syncthreads();
        if (tid < 64) scan_find(hist, nb, k, sbd);
        __syncthreads();
        ull d2 = sbd[0]; unsigned kp2 = (unsigned)sbd[1];
        unsigned c2 = hist[SIX((int)d2)];
        pfx |= d2 << sh; k = kp2;
        if (kp2 == c2) break;                    // whole bin taken -> thr exact
      }
    }
    thr = pfx;   // exactly TOPK valid elements have pk >= thr (keys unique)
  }
  if (tid == 0) thrKey[b] = thr;
}

// ---------------- K2b: element-parallel class-bucket scatter (200 blocks) ----------------
__global__ __launch_bounds__(1024) void scatter_kernel(const ull* __restrict__ pkArr,
    const ull* __restrict__ thrKey, const unsigned char* __restrict__ cls8,
    ull* __restrict__ bucket, unsigned* __restrict__ bucketCnt) {
  const int b = blockIdx.y;
  const int i = blockIdx.x * 1024 + (int)threadIdx.x;
  if (i >= N_PRED) return;
  const ull thr = thrKey[b];                    // uniform -> scalar load
  ull pv = pkArr[(size_t)b * N_PRED + i];
  if (pv >= thr && (pv >> 63)) {                // validity bit == reference tvalid
    unsigned idx = ~(unsigned)(pv & 0xFFFFFFFFull);   // == i, but derive from key as before
    int c = (int)cls8[(size_t)b * N_PRED + idx];
    unsigned pos = atomicAdd(&bucketCnt[b * NCLS + c], 1u);
    if (pos < CAP) bucket[((size_t)b * NCLS + c) * CAP + pos] = pv;
  }
}

// ---------------- K3: per-(batch,class) rank-sort + register-bitmask greedy NMS ----------------
__global__ __launch_bounds__(64) void nms_kernel(const ull* __restrict__ bucket,
    const unsigned* __restrict__ bucketCnt, const float* __restrict__ pred,
    ull* __restrict__ keptPk, float4* __restrict__ keptBox, float2* __restrict__ keptSC,
    unsigned* __restrict__ keptCnt) {
  const int c = blockIdx.x, b = blockIdx.y, lane = (int)threadIdx.x;
  __shared__ ull su[CAPB];      // unsorted
  __shared__ ull spk[CAPB];     // rank-ordered (descending pk)
  __shared__ float4 sob[CAPB];  // offset boxes
  __shared__ float4 srb[CAPB];  // raw boxes
  unsigned kxu = bucketCnt[b * NCLS + c];
  int kx = (kxu > CAPB) ? CAPB : (int)kxu;
  if (kx == 0) return;
  const float cf = (float)c;
  const float off = __fmul_rn(cf, MAXWH);
  const ull* bk = bucket + ((size_t)b * NCLS + c) * CAP;
  for (int i = lane; i < kx; i += 64) su[i] = bk[i];
  __syncthreads();
  // rank-by-count sort (keys unique): rank = #keys greater -> descending order
  {
    ull mine[4]; int rk[4] = {0, 0, 0, 0};
    #pragma unroll
    for (int r = 0; r < 4; ++r) mine[r] = (r * 64 + lane < kx) ? su[r * 64 + lane] : 0ull;
    for (int j = 0; j < kx; ++j) {          // uniform loop, LDS broadcast
      ull x = su[j];
      #pragma unroll
      for (int r = 0; r < 4; ++r) rk[r] += (x > mine[r]) ? 1 : 0;
    }
    #pragma unroll
    for (int r = 0; r < 4; ++r)
      if (r * 64 + lane < kx) spk[rk[r]] = mine[r];
  }
  __syncthreads();
  // single gather: derive raw + offset boxes from pred (bit-identical to reference)
  for (int i = lane; i < kx; i += 64) {
    unsigned idx = ~(unsigned)(spk[i] & 0xFFFFFFFFull);
    float4 t0; __builtin_memcpy(&t0, pred + ((size_t)b * N_PRED + idx) * ROWW, 16);
    float hw = __fmul_rn(t0.z, 0.5f), hh = __fmul_rn(t0.w, 0.5f);
    float4 rb = make_float4(__fsub_rn(t0.x, hw), __fsub_rn(t0.y, hh),
                            __fadd_rn(t0.x, hw), __fadd_rn(t0.y, hh));
    srb[i] = rb;
    sob[i] = make_float4(__fadd_rn(rb.x, off), __fadd_rn(rb.y, off),
                         __fadd_rn(rb.z, off), __fadd_rn(rb.w, off));
  }
  __syncthreads();
  // parallel upper-triangle suppression matrix -> per-lane register masks
  ull rowm[4][4] = {{0ull}};
  #pragma unroll
  for (int r = 0; r < 4; ++r) {
    if (r * 64 < kx) {
      const int i = r * 64 + lane;
      const bool act = i < kx;
      float4 A = sob[act ? i : 0];
      float areaA = __fmul_rn(__fsub_rn(A.z, A.x), __fsub_rn(A.w, A.y));
      #pragma unroll
      for (int w = 0; w < 4; ++w) {
        if (w >= r && w * 64 < kx) {
          ull m = 0ull;
          int jmax = kx - w * 64; if (jmax > 64) jmax = 64;
          for (int jj = 0; jj < jmax; ++jj) {
            const int j = w * 64 + jj;
            float4 Bx = sob[j];             // broadcast read
            float areaB = __fmul_rn(__fsub_rn(Bx.z, Bx.x), __fsub_rn(Bx.w, Bx.y));
            float wx = fmaxf(__fsub_rn(fminf(A.z, Bx.z), fmaxf(A.x, Bx.x)), 0.0f);
            float wy = fmaxf(__fsub_rn(fminf(A.w, Bx.w), fmaxf(A.y, Bx.y)), 0.0f);
            float inter = __fmul_rn(wx, wy);
            float denom = __fadd_rn(__fsub_rn(__fadd_rn(areaA, areaB), inter), 1e-7f);
            float iou = __fdiv_rn(inter, denom);
            if (act && j > i && iou > IOU_T) m |= 1ull << jj;
          }
          rowm[r][w] = m;
        }
      }
    }
  }
  // sequential greedy scan, registers + shfl only (no LDS, no barriers)
  ull alive[4];
  #pragma unroll
  for (int w = 0; w < 4; ++w) {
    int rem = kx - w * 64;
    alive[w] = (rem >= 64) ? ~0ull : (rem > 0 ? ((1ull << rem) - 1ull) : 0ull);
  }
  #pragma unroll
  for (int w = 0; w < 4; ++w) {
    if (w * 64 < kx) {
      int bmax = kx - w * 64; if (bmax > 64) bmax = 64;
      for (int bit = 0; bit < bmax; ++bit) {
        if ((alive[w] >> bit) & 1ull) {     // uniform across lanes
          #pragma unroll
          for (int w2 = 0; w2 < 4; ++w2) {
            if (w2 >= w && w2 * 64 < kx) {
              ull row = __shfl(rowm[w][w2], bit, 64);
              alive[w2] &= ~row;
            }
          }
        }
      }
    }
  }
  // emit kept (order arbitrary; K4 ranks by pk); boxes from LDS
  int tot = 0;
  #pragma unroll
  for (int w = 0; w < 4; ++w) tot += (int)__popcll(alive[w]);
  unsigned gbase = 0;
  if (lane == 0) gbase = atomicAdd(&keptCnt[b], (unsigned)tot);
  gbase = __shfl(gbase, 0, 64);
  unsigned pre = 0;
  #pragma unroll
  for (int w = 0; w < 4; ++w) {
    if (w * 64 < kx) {
      ull aw = alive[w];
      int i = w * 64 + lane;
      bool kp = (i < kx) && ((aw >> lane) & 1ull);
      if (kp) {
        unsigned pos = gbase + pre + (unsigned)__popcll(aw & ((1ull << lane) - 1ull));
        if (pos < TOPK) {
          ull p = spk[i];
          keptPk[(size_t)b * TOPK + pos] = p;
          keptBox[(size_t)b * TOPK + pos] = srb[i];
          keptSC[(size_t)b * TOPK + pos] =
              make_float2(__uint_as_float((unsigned)(p >> 32) & 0x7FFFFFFFu), cf);
        }
      }
      pre += (unsigned)__popcll(aw);
    }
  }
}

// ---------------- K4: top-max_det of kept (radix early-exit + rank-by-count) -> output ----------------
__global__ __launch_bounds__(K4T) void out_kernel(const ull* __restrict__ keptPk,
    const float4* __restrict__ keptBox, const float2* __restrict__ keptSC,
    const unsigned* __restrict__ keptCnt, float* __restrict__ out, int maxdet) {
  __shared__ unsigned hist[2112];
  __shared__ ull sbd[2];
  __shared__ ull sPk[SELN];
  __shared__ int sSlot[SELN];
  __shared__ unsigned scnt;
  const int b = blockIdx.x;
  const int tid = (int)threadIdx.x;
  float* ob = out + (size_t)b * maxdet * 6;
  const unsigned K = keptCnt[b];
  const unsigned kk = (K < (unsigned)maxdet) ? K : (unsigned)maxdet;
  // rows 0..kk-1 are always overwritten; zero only the tail
  for (int i = (int)kk * 6 + tid; i < maxdet * 6; i += K4T) ob[i] = 0.0f;
  if (kk == 0) return;
  ull v[MAXE4];
  #pragma unroll
  for (int e = 0; e < MAXE4; ++e) {
    unsigned i = (unsigned)tid + e * K4T;
    v[e] = (i < K) ? keptPk[(size_t)b * TOPK + i] : 0ull;
  }
  ull thr = 1ull;                       // K <= maxdet: take all (kept pk always nonzero)
  if (K > (unsigned)maxdet) {
    unsigned k = kk;
    ull pfx = 0;
    const int shifts[6] = {53, 42, 31, 20, 9, 0};
    const int widths[6] = {11, 11, 11, 11, 11, 9};
    for (int p = 0; p < 6; ++p) {
      const int sh = shifts[p];
      const int nb = 1 << widths[p];
      for (int i = tid; i < 2112; i += K4T) hist[i] = 0;
      __syncthreads();
      const int hb = sh + widths[p];
      const ull hm = (hb >= 64) ? 0ull : ~((1ull << hb) - 1ull);
      #pragma unroll
      for (int e = 0; e < MAXE4; ++e) {
        ull pv = v[e];
        if (pv != 0ull && (pv & hm) == pfx)
          atomicAdd(&hist[SIX((int)((pv >> sh) & (ull)(nb - 1)))], 1u);
      }
      __syncthreads();
      if (tid < 64) scan_find(hist, nb, k, sbd);
      __syncthreads();
      ull d = sbd[0]; unsigned kp = (unsigned)sbd[1];
      unsigned c = hist[SIX((int)d)];
      pfx |= d << sh; k = kp;
      if (kp == c) break;               // whole bin -> thr exact
      __syncthreads();
    }
    thr = pfx;
  }
  if (tid == 0) scnt = 0;
  __syncthreads();
  const int lane = tid & 63;
  #pragma unroll
  for (int e = 0; e < MAXE4; ++e) {
    unsigned i = (unsigned)tid + e * K4T;
    bool sel = (i < K) && (v[e] >= thr);
    ull m = __ballot(sel);
    if (m) {
      unsigned basep = 0;
      if (lane == 0) basep = atomicAdd(&scnt, (unsigned)__popcll(m));
      basep = __shfl(basep, 0, 64);
      if (sel) {
        unsigned pos = basep + (unsigned)__popcll(m & ((1ull << lane) - 1ull));
        if (pos < SELN) { sPk[pos] = v[e]; sSlot[pos] = (int)i; }
      }
    }
  }
  __syncthreads();
  const int n = (int)scnt;              // == kk (exact threshold, unique keys)
  // rank-by-count: output row = #keys greater (descending pk = reference order)
  for (int i = tid; i < n; i += K4T) {
    ull mypk = sPk[i];
    int rank = 0;
    for (int j = 0; j < n; ++j) rank += (sPk[j] > mypk) ? 1 : 0;   // uniform broadcast
    if (rank < maxdet) {
      int slot = sSlot[i];
      float4 bx = keptBox[(size_t)b * TOPK + slot];
      float2 sc = keptSC[(size_t)b * TOPK + slot];
      float* dst = ob + (size_t)rank * 6;
      dst[0] = bx.x; dst[1] = bx.y; dst[2] = bx.z; dst[3] = bx.w;
      dst[4] = sc.x; dst[5] = sc.y;
    }
  }
}

extern "C" void kernel_launch(void* const* d_in, const int* in_sizes, int n_in,
                              void* d_out, int out_size, void* d_ws, size_t ws_size,
                              hipStream_t stream) {
  const float* pred = (const float*)d_in[0];
  const int B = in_sizes[0] / (N_PRED * ROWW);
  const int maxdet = out_size / (B * 6);

  char* p = (char*)d_ws;
  auto carve = [&](size_t bytes) { char* r = p; p += (bytes + 255) & ~(size_t)255; return (void*)r; };
  ull*           pk       = (ull*)carve((size_t)B * N_PRED * 8);
  unsigned char* cls8     = (unsigned char*)carve((size_t)B * N_PRED);
  unsigned*      bucketCnt= (unsigned*)carve((size_t)B * NCLS * 4);
  unsigned*      keptCnt  = (unsigned*)carve((size_t)B * 4);
  ull*           thrKey   = (ull*)carve((size_t)B * 8);
  ull*      bucket  = (ull*)carve((size_t)B * NCLS * CAP * 8);
  ull*      keptPk  = (ull*)carve((size_t)B * TOPK * 8);
  float4*   keptBox = (float4*)carve((size_t)B * TOPK * 16);
  float2*   keptSC  = (float2*)carve((size_t)B * TOPK * 8);

  prep_kernel<<<dim3((N_PRED + PROWS - 1) / PROWS, B), PTPB, 0, stream>>>(pred, pk, cls8);
  thresh_kernel<<<B, K2T, 0, stream>>>(pk, thrKey, bucketCnt, keptCnt);
  scatter_kernel<<<dim3((N_PRED + 1023) / 1024, B), 1024, 0, stream>>>(
      pk, thrKey, cls8, bucket, bucketCnt);
  nms_kernel<<<dim3(NCLS, B), 64, 0, stream>>>(bucket, bucketCnt, pred,
                                               keptPk, keptBox, keptSC, keptCnt);
  out_kernel<<<B, K4T, 0, stream>>>(keptPk, keptBox, keptSC, keptCnt, (float*)d_out, maxdet);
}